// Round 6
// baseline (147.694 us; speedup 1.0000x reference)
//
#include <hip/hip_runtime.h>
#include <hip/hip_bf16.h>
#include <math.h>

#define N_ROWS 32768
#define C_DIM 256
#define K_CODES 1024
#define DECAY_F 0.99f
#define ONE_MINUS_DECAY 0.01f
#define EPS_F 1e-5f

// Output offsets (floats)
#define OFF_QST 0
#define OFF_EMB 8388608
#define OFF_CS  8650752
#define OFF_DW  8651776
#define OFF_LOSS 8913920
#define OFF_PERP 8913921

// Workspace layout (float offsets)
#define WS_ESQ   0         // 1024
#define WS_BP    1024      // 262144 floats = 1MB of bf16-packed E (hi+lo)
#define WS_DWT   263168    // 262144  dwT[k][c]
#define WS_CNT   525312    // 1024
#define WS_LOSSP 526336    // 1024
#define WS_INVSM 534528    // 1024
#define WS_IDX   535552    // 32768 ints

typedef __attribute__((ext_vector_type(8))) short bf16x8;
typedef __attribute__((ext_vector_type(4))) float f32x4;
typedef union { short s[8]; unsigned u[4]; bf16x8 v; } fragu;

#define GLD_LDS16(g, l) __builtin_amdgcn_global_load_lds( \
    (const __attribute__((address_space(1))) void*)(g),   \
    (__attribute__((address_space(3))) void*)(l), 16, 0, 0)

__device__ inline unsigned bf16rne(float f) {
    unsigned u = __float_as_uint(f);
    return (u + 0x7fffu + ((u >> 16) & 1u)) >> 16;
}

__device__ inline unsigned pack_bf16_pair(float a, float b) {
    float2 f2; f2.x = a; f2.y = b;
    __hip_bfloat162 h = __float22bfloat162_rn(f2);   // v_cvt_pk_bf16_f32
    union { __hip_bfloat162 b2; unsigned u; } cv;
    cv.b2 = h;
    return cv.u;
}

// ---------------- prep: esq[k] = sum_d E[d,k]^2 ----------------
__global__ __launch_bounds__(256) void esq_kernel(const float* __restrict__ E,
                                                  float* __restrict__ esq) {
    int k = blockIdx.x * 256 + threadIdx.x;
    float s = 0.f;
    #pragma unroll 8
    for (int d = 0; d < C_DIM; ++d) {
        float e = E[d * K_CODES + k];
        s += e * e;
    }
    esq[k] = s;
}

// ---------------- prep: pack E into MFMA B-fragment layout ----------------
// Group g = ctg*16 + ks (ctg: col-tile 0..63; ks 0..7 = e_hi, 8..15 = e_lo).
// Lane l: 8 bf16, col = ctg*16+(l&15), k = (ks&7)*32 + (l>>4)*8 + b.
__global__ __launch_bounds__(256) void b_pack_kernel(const float* __restrict__ E,
                                                     short* __restrict__ Bp) {
    int tid = threadIdx.x;
    int g = blockIdx.x * 4 + (tid >> 6);
    int l = tid & 63;
    int ct = g >> 4, ks = g & 15;
    int j = ct * 16 + (l & 15);
    int kbase = (ks & 7) * 32 + (l >> 4) * 8;
    fragu out;
    #pragma unroll
    for (int b = 0; b < 8; ++b) {
        float e = E[(kbase + b) * K_CODES + j];
        unsigned hi = bf16rne(e);
        if (ks < 8) out.s[b] = (short)hi;
        else        out.s[b] = (short)bf16rne(e - __uint_as_float(hi << 16));
    }
    *(bf16x8*)(Bp + ((size_t)g * 64 + l) * 8) = out.v;
}

// ---------------- MFMA distance + fused argmax, LDS-staged B ----------------
// 512 blocks x 8 waves (512 thr). Block = 64 rows x 1024 cols.
// Wave (rg=w>>2, qt=w&3) = 32 rows (2 row-tiles) x 256 cols (quarter).
// Stage s = cc*8+ks (cc 0..3 = 64-col chunk per quarter, ks 0..7):
// 32 groups x 1KB = 32KB (4 qt x 4 ct x hi/lo), double-buffered.
__global__ __launch_bounds__(512) void mfma_dist_kernel(
    const float* __restrict__ X,
    const short* __restrict__ Bp,
    const float* __restrict__ esq,
    int* __restrict__ idxbuf)
{
    __shared__ short sB[2][16384];    // 2 x 32KB
    __shared__ float sval[8][32];
    __shared__ int   sidx[8][32];

    int tid = threadIdx.x;
    int w = tid >> 6, l = tid & 63;
    int rg = w >> 2;          // row group 0..1
    int qt = w & 3;           // col quarter 0..3
    int row0 = blockIdx.x * 64 + rg * 32;
    int arow = l & 15;
    int aseg = l >> 4;
    const float* Xr0 = X + (size_t)(row0 + arow) * C_DIM + aseg * 8;
    const float* Xr1 = Xr0 + 16 * C_DIM;

    float best[8];
    int bidx[8];
    #pragma unroll
    for (int i = 0; i < 8; ++i) { best[i] = -INFINITY; bidx[i] = 0; }

    // stage s into buffer b: 4 loads/thread; q = i*8+w in 0..31 decodes
    // (qt_=q>>3, ct=(q>>1)&3, hilo=q&1); src group (qt_*16+cc*4+ct)*16+ks+hilo*8.
#define STAGE(s, b) do {                                                     \
        int cc_ = (s) >> 3, ks_ = (s) & 7;                                   \
        _Pragma("unroll")                                                    \
        for (int i = 0; i < 4; ++i) {                                        \
            int q = i * 8 + w;                                               \
            int hilo = q & 1, ct_ = (q >> 1) & 3, qt_ = q >> 3;              \
            int ctg = qt_ * 16 + cc_ * 4 + ct_;                              \
            const short* src = Bp + ((size_t)(ctg * 16 + ks_ + hilo * 8) * 64 \
                                     + l) * 8;                               \
            GLD_LDS16(src, &sB[b][q * 512]);                                 \
        }                                                                    \
    } while (0)

    STAGE(0, 0);
    __syncthreads();

    for (int cc = 0; cc < 4; ++cc) {
        f32x4 acc[2][4];
        #pragma unroll
        for (int rt = 0; rt < 2; ++rt)
            #pragma unroll
            for (int ct = 0; ct < 4; ++ct)
                acc[rt][ct] = (f32x4)(0.f);

        for (int ks = 0; ks < 8; ++ks) {
            int s = cc * 8 + ks;
            int buf = s & 1;
            if (s < 31) STAGE(s + 1, buf ^ 1);

            // A fragments (fp32 -> bf16 hi/lo, in-register)
            float xf0[8], xf1[8];
            *(float4*)(xf0)     = *(const float4*)(Xr0 + ks * 32);
            *(float4*)(xf0 + 4) = *(const float4*)(Xr0 + ks * 32 + 4);
            *(float4*)(xf1)     = *(const float4*)(Xr1 + ks * 32);
            *(float4*)(xf1 + 4) = *(const float4*)(Xr1 + ks * 32 + 4);
            fragu ah0, al0, ah1, al1;
            #pragma unroll
            for (int p = 0; p < 4; ++p) {
                float a = xf0[2 * p], b = xf0[2 * p + 1];
                unsigned h = pack_bf16_pair(a, b);
                ah0.u[p] = h;
                al0.u[p] = pack_bf16_pair(a - __uint_as_float(h << 16),
                                          b - __uint_as_float(h & 0xffff0000u));
                float c = xf1[2 * p], d = xf1[2 * p + 1];
                unsigned h2 = pack_bf16_pair(c, d);
                ah1.u[p] = h2;
                al1.u[p] = pack_bf16_pair(c - __uint_as_float(h2 << 16),
                                          d - __uint_as_float(h2 & 0xffff0000u));
            }
            const short* lbase = &sB[buf][qt * 4096 + l * 8];
            __builtin_amdgcn_s_setprio(1);
            #pragma unroll
            for (int ct = 0; ct < 4; ++ct) {
                bf16x8 bh = *(const bf16x8*)(lbase + ct * 1024);
                bf16x8 bl = *(const bf16x8*)(lbase + ct * 1024 + 512);
                acc[0][ct] = __builtin_amdgcn_mfma_f32_16x16x32_bf16(ah0.v, bh, acc[0][ct], 0, 0, 0);
                acc[1][ct] = __builtin_amdgcn_mfma_f32_16x16x32_bf16(ah1.v, bh, acc[1][ct], 0, 0, 0);
                acc[0][ct] = __builtin_amdgcn_mfma_f32_16x16x32_bf16(al0.v, bh, acc[0][ct], 0, 0, 0);
                acc[1][ct] = __builtin_amdgcn_mfma_f32_16x16x32_bf16(al1.v, bh, acc[1][ct], 0, 0, 0);
                acc[0][ct] = __builtin_amdgcn_mfma_f32_16x16x32_bf16(ah0.v, bl, acc[0][ct], 0, 0, 0);
                acc[1][ct] = __builtin_amdgcn_mfma_f32_16x16x32_bf16(ah1.v, bl, acc[1][ct], 0, 0, 0);
            }
            __builtin_amdgcn_s_setprio(0);
            __syncthreads();   // stage s+1 landed; all waves done with buf
        }
        // epilogue for this 64-col chunk of our quarter
        #pragma unroll
        for (int rt = 0; rt < 2; ++rt) {
            #pragma unroll
            for (int ct = 0; ct < 4; ++ct) {
                int col = qt * 256 + cc * 64 + ct * 16 + (l & 15);
                float sq = esq[col];
                #pragma unroll
                for (int v = 0; v < 4; ++v) {
                    float s = 2.f * acc[rt][ct][v] - sq;
                    int bi = rt * 4 + v;
                    if (s > best[bi]) { best[bi] = s; bidx[bi] = col; }
                }
            }
        }
    }
#undef STAGE

    // reduce across the 16 lanes holding different cols of the same rows
    #pragma unroll
    for (int bi = 0; bi < 8; ++bi) {
        float bv = best[bi]; int ix = bidx[bi];
        #pragma unroll
        for (int m = 1; m < 16; m <<= 1) {
            float ov = __shfl_xor(bv, m, 64);
            int oi = __shfl_xor(ix, m, 64);
            if (ov > bv || (ov == bv && oi < ix)) { bv = ov; ix = oi; }
        }
        if ((l & 15) == 0) {
            int rt = bi >> 2, v = bi & 3;
            sval[w][rt * 16 + aseg * 4 + v] = bv;
            sidx[w][rt * 16 + aseg * 4 + v] = ix;
        }
    }
    __syncthreads();
    // merge 4 col-quarters: 64 rows per block. qt ascending => lowest col wins ties.
    if (tid < 64) {
        int r = tid & 31;
        int g2 = tid >> 5;                 // row group
        float bv = sval[g2 * 4][r];
        int ix = sidx[g2 * 4][r];
        #pragma unroll
        for (int q2 = 1; q2 < 4; ++q2) {
            float ov = sval[g2 * 4 + q2][r];
            int oi = sidx[g2 * 4 + q2][r];
            if (ov > bv) { bv = ov; ix = oi; }
        }
        idxbuf[blockIdx.x * 64 + g2 * 32 + r] = ix;
    }
}

// ---------------- per-code: quant_st, dw, counts, loss (no fp atomics) ----
#define QCAP 2048
__global__ __launch_bounds__(256) void percode_kernel(
    const float* __restrict__ X,
    const float* __restrict__ E,
    const int* __restrict__ idxbuf,
    float* __restrict__ out_qst,
    float* __restrict__ dwT,
    float* __restrict__ counts,
    float* __restrict__ lossp)
{
    __shared__ int queue[4][QCAP];
    __shared__ float redA[4][256];
    __shared__ float redL[4];
    __shared__ int redC[4];

    int k = blockIdx.x;
    int tid = threadIdx.x;
    int w = tid >> 6, lane = tid & 63;

    float q0 = E[(lane * 4 + 0) * K_CODES + k];
    float q1 = E[(lane * 4 + 1) * K_CODES + k];
    float q2 = E[(lane * 4 + 2) * K_CODES + k];
    float q3 = E[(lane * 4 + 3) * K_CODES + k];

    const float4* X4 = (const float4*)X;
    float4* O4 = (float4*)out_qst;
    const int4* I4 = (const int4*)idxbuf;

    float a0 = 0.f, a1 = 0.f, a2 = 0.f, a3 = 0.f, ls = 0.f;
    int tot = 0, cnt = 0;
    unsigned long long below_mask = (lane == 0) ? 0ull : (~0ull >> (64 - lane));

#define DRAIN() do {                                                        \
        for (int qi = 0; qi < cnt; ++qi) {                                  \
            int row = queue[w][qi];                                         \
            float4 x = X4[(size_t)row * 64 + lane];                         \
            float d0 = q0 - x.x, d1 = q1 - x.y, d2 = q2 - x.z, d3 = q3 - x.w; \
            float4 o; o.x = x.x + d0; o.y = x.y + d1;                       \
            o.z = x.z + d2; o.w = x.w + d3;                                 \
            O4[(size_t)row * 64 + lane] = o;                                \
            a0 += x.x; a1 += x.y; a2 += x.z; a3 += x.w;                     \
            ls += d0 * d0 + d1 * d1 + d2 * d2 + d3 * d3;                    \
        }                                                                   \
        tot += cnt; cnt = 0;                                                \
    } while (0)

    int base = w * 2048;   // int4 units
    for (int it = 0; it < 32; ++it) {
        int4 v = I4[base + it * 64 + lane];
        int rbase = (base + it * 64 + lane) * 4;
        #pragma unroll
        for (int j = 0; j < 4; ++j) {
            int vj = (j == 0) ? v.x : (j == 1) ? v.y : (j == 2) ? v.z : v.w;
            bool p = (vj == k);
            unsigned long long mask = __ballot(p);
            if (p) queue[w][cnt + __popcll(mask & below_mask)] = rbase + j;
            cnt += __popcll(mask);
        }
        if (cnt >= QCAP - 256) DRAIN();
    }
    DRAIN();
#undef DRAIN

    redA[w][lane * 4 + 0] = a0;
    redA[w][lane * 4 + 1] = a1;
    redA[w][lane * 4 + 2] = a2;
    redA[w][lane * 4 + 3] = a3;
    #pragma unroll
    for (int m = 1; m < 64; m <<= 1) ls += __shfl_xor(ls, m, 64);
    if (lane == 0) { redL[w] = ls; redC[w] = tot; }
    __syncthreads();

    float dw = redA[0][tid] + redA[1][tid] + redA[2][tid] + redA[3][tid];
    dwT[(size_t)k * C_DIM + tid] = dw;
    if (tid == 0) {
        lossp[k] = redL[0] + redL[1] + redL[2] + redL[3];
        counts[k] = (float)(redC[0] + redC[1] + redC[2] + redC[3]);
    }
}

// ---------------- finalize 1: cs EMA, n, smoothing, entropy, loss ----------------
__global__ __launch_bounds__(1024) void finalize1_kernel(const float* __restrict__ ema_cs,
                                                         const float* __restrict__ counts,
                                                         const float* __restrict__ lossp,
                                                         float* __restrict__ out,
                                                         float* __restrict__ inv_sm) {
    int k = threadIdx.x;
    __shared__ double red[1024];
    float cs = counts[k];
    float necs = ema_cs[k] * DECAY_F + cs * ONE_MINUS_DECAY;
    out[OFF_CS + k] = necs;

    red[k] = (double)necs;
    __syncthreads();
    for (int s = 512; s > 0; s >>= 1) {
        if (k < s) red[k] += red[k + s];
        __syncthreads();
    }
    float nf = (float)red[0];
    __syncthreads();

    float sm = (necs + EPS_F) / (nf + (float)K_CODES * EPS_F) * nf;
    inv_sm[k] = 1.0f / sm;

    float avg = cs * (1.0f / (float)N_ROWS);
    red[k] = (double)(avg * logf(avg + 1e-10f));
    __syncthreads();
    for (int s = 512; s > 0; s >>= 1) {
        if (k < s) red[k] += red[k + s];
        __syncthreads();
    }
    double ent = red[0];
    __syncthreads();

    red[k] = (double)lossp[k];
    __syncthreads();
    for (int s = 512; s > 0; s >>= 1) {
        if (k < s) red[k] += red[k + s];
        __syncthreads();
    }
    if (k == 0) {
        double eloss = red[0] / (double)(N_ROWS * C_DIM);
        out[OFF_LOSS] = (float)(0.25 * eloss);
        out[OFF_PERP] = expf((float)(-ent));
    }
}

// ---------------- finalize 2: new_ema_dw, new_embeddings ----------------
__global__ __launch_bounds__(256) void finalize2_kernel(const float* __restrict__ ema_dw,
                                                        const float* __restrict__ dwT,
                                                        const float* __restrict__ inv_sm,
                                                        float* __restrict__ out) {
    int i = blockIdx.x * 256 + threadIdx.x;
    int c = i >> 10;
    int k = i & 1023;
    float ndw = ema_dw[i] * DECAY_F + dwT[k * C_DIM + c] * ONE_MINUS_DECAY;
    out[OFF_DW + i] = ndw;
    out[OFF_EMB + i] = ndw * inv_sm[k];
}

extern "C" void kernel_launch(void* const* d_in, const int* in_sizes, int n_in,
                              void* d_out, int out_size, void* d_ws, size_t ws_size,
                              hipStream_t stream) {
    const float* inputs = (const float*)d_in[0];
    const float* E      = (const float*)d_in[1];
    const float* ema_cs = (const float*)d_in[2];
    const float* ema_dw = (const float*)d_in[3];
    float* out = (float*)d_out;
    float* ws  = (float*)d_ws;

    float* esq    = ws + WS_ESQ;
    short* Bp     = (short*)(ws + WS_BP);
    float* dwT    = ws + WS_DWT;
    float* counts = ws + WS_CNT;
    float* lossp  = ws + WS_LOSSP;
    float* inv_sm = ws + WS_INVSM;
    int*   idxbuf = (int*)(ws + WS_IDX);

    esq_kernel<<<K_CODES / 256, 256, 0, stream>>>(E, esq);
    b_pack_kernel<<<256, 256, 0, stream>>>(E, Bp);
    mfma_dist_kernel<<<N_ROWS / 64, 512, 0, stream>>>(inputs, Bp, esq, idxbuf);
    percode_kernel<<<K_CODES, 256, 0, stream>>>(inputs, E, idxbuf, out + OFF_QST,
                                                dwT, counts, lossp);
    finalize1_kernel<<<1, 1024, 0, stream>>>(ema_cs, counts, lossp, out, inv_sm);
    finalize2_kernel<<<(C_DIM * K_CODES) / 256, 256, 0, stream>>>(ema_dw, dwT, inv_sm, out);
}

// Round 7
// 101.269 us; speedup vs baseline: 1.4584x; 1.4584x over previous
//
#include <hip/hip_runtime.h>
#include <hip/hip_bf16.h>
#include <math.h>

#define N_ROWS 32768
#define C_DIM 256
#define K_CODES 1024
#define DECAY_F 0.99f
#define ONE_MINUS_DECAY 0.01f
#define EPS_F 1e-5f

// Output offsets (floats)
#define OFF_QST 0
#define OFF_EMB 8388608
#define OFF_CS  8650752
#define OFF_DW  8651776
#define OFF_LOSS 8913920
#define OFF_PERP 8913921

// Workspace layout (float offsets)
#define WS_ESQ   0         // 1024
#define WS_BP    1024      // 131072 floats = 512KB bf16-packed E (hi only)
#define WS_DWT   263168    // 262144  dwT[k][c]
#define WS_CNT   525312    // 1024
#define WS_LOSSP 526336    // 1024
#define WS_INVSM 534528    // 1024
#define WS_IDX   535552    // 32768 ints

typedef __attribute__((ext_vector_type(8))) short bf16x8;
typedef __attribute__((ext_vector_type(4))) float f32x4;
typedef union { short s[8]; unsigned u[4]; bf16x8 v; } fragu;

#define GLD_LDS16(g, l) __builtin_amdgcn_global_load_lds( \
    (const __attribute__((address_space(1))) void*)(g),   \
    (__attribute__((address_space(3))) void*)(l), 16, 0, 0)

__device__ inline unsigned bf16rne(float f) {
    unsigned u = __float_as_uint(f);
    return (u + 0x7fffu + ((u >> 16) & 1u)) >> 16;
}

__device__ inline unsigned pack_bf16_pair(float a, float b) {
    float2 f2; f2.x = a; f2.y = b;
    __hip_bfloat162 h = __float22bfloat162_rn(f2);   // v_cvt_pk_bf16_f32
    union { __hip_bfloat162 b2; unsigned u; } cv;
    cv.b2 = h;
    return cv.u;
}

// ---------------- prep: esq[k] = sum_d E[d,k]^2 (fp32 exact) --------------
__global__ __launch_bounds__(256) void esq_kernel(const float* __restrict__ E,
                                                  float* __restrict__ esq) {
    int k = blockIdx.x * 256 + threadIdx.x;
    float s = 0.f;
    #pragma unroll 8
    for (int d = 0; d < C_DIM; ++d) {
        float e = E[d * K_CODES + k];
        s += e * e;
    }
    esq[k] = s;
}

// ---------------- prep: pack E (hi bf16 only) into MFMA B layout ----------
// Group g = ctg*8 + ks (ctg 0..63 col-tile, ks 0..7 k-step).
// Lane l: 8 bf16, col = ctg*16+(l&15), k = ks*32 + (l>>4)*8 + b.
__global__ __launch_bounds__(256) void b_pack_kernel(const float* __restrict__ E,
                                                     short* __restrict__ Bp) {
    int tid = threadIdx.x;
    int g = blockIdx.x * 4 + (tid >> 6);
    int l = tid & 63;
    int ct = g >> 3, ks = g & 7;
    int j = ct * 16 + (l & 15);
    int kbase = ks * 32 + (l >> 4) * 8;
    fragu out;
    #pragma unroll
    for (int b = 0; b < 8; ++b)
        out.s[b] = (short)bf16rne(E[(kbase + b) * K_CODES + j]);
    *(bf16x8*)(Bp + ((size_t)g * 64 + l) * 8) = out.v;
}

// ---------------- MFMA distance + fused argmax ----------------
// 512 blocks x 8 waves (512 thr). Block = 64 rows x 1024 cols.
// Wave (rg=w>>2, qt=w&3) = 32 rows (2 row-tiles) x 256 cols (quarter).
// A (bf16 hi) held in registers for the whole kernel (converted once).
// Phases s = cc*8+ks (cc 0..1 = 128-col half-quarter, ks 0..7).
// Stage = 32 groups x 1KB = 32KB (4 qt x 8 ct), double-buffered.
// Counted vmcnt: stage s+1 issued before waiting stage s at vmcnt(4).
__global__ __launch_bounds__(512) void mfma_dist_kernel(
    const float* __restrict__ X,
    const short* __restrict__ Bp,
    const float* __restrict__ esq,
    int* __restrict__ idxbuf)
{
    __shared__ short sB[2][16384];    // 2 x 32KB
    __shared__ float sval[8][32];
    __shared__ int   sidx[8][32];

    int tid = threadIdx.x;
    int w = tid >> 6, l = tid & 63;
    int rg = w >> 2;          // row group 0..1
    int qt = w & 3;           // col quarter 0..3
    int row0 = blockIdx.x * 64 + rg * 32;
    int arow = l & 15;
    int aseg = l >> 4;
    const float* Xr0 = X + (size_t)(row0 + arow) * C_DIM + aseg * 8;
    const float* Xr1 = Xr0 + 16 * C_DIM;

    // stage s into buffer b: 4 loads/thread; q = i*8+w in 0..31:
    // qt_=q>>3, ct_=q&7; src group ctg*8+ks with ctg = qt_*16 + cc*8 + ct_.
#define STAGE(cc_, ks_, b) do {                                              \
        _Pragma("unroll")                                                    \
        for (int i = 0; i < 4; ++i) {                                        \
            int q = i * 8 + w;                                               \
            int ct_ = q & 7, qt_ = q >> 3;                                   \
            int ctg = qt_ * 16 + (cc_) * 8 + ct_;                            \
            const short* src = Bp + ((size_t)(ctg * 8 + (ks_)) * 64 + l) * 8;\
            GLD_LDS16(src, &sB[b][q * 512]);                                 \
        }                                                                    \
    } while (0)

    STAGE(0, 0, 0);   // stage s=0

    // ---- prologue: load + convert all A fragments (once) ----
    bf16x8 ahs0[8], ahs1[8];
    #pragma unroll
    for (int ks = 0; ks < 8; ++ks) {
        float xf0[8], xf1[8];
        *(float4*)(xf0)     = *(const float4*)(Xr0 + ks * 32);
        *(float4*)(xf0 + 4) = *(const float4*)(Xr0 + ks * 32 + 4);
        *(float4*)(xf1)     = *(const float4*)(Xr1 + ks * 32);
        *(float4*)(xf1 + 4) = *(const float4*)(Xr1 + ks * 32 + 4);
        fragu a0, a1;
        #pragma unroll
        for (int p = 0; p < 4; ++p) {
            a0.u[p] = pack_bf16_pair(xf0[2 * p], xf0[2 * p + 1]);
            a1.u[p] = pack_bf16_pair(xf1[2 * p], xf1[2 * p + 1]);
        }
        ahs0[ks] = a0.v;
        ahs1[ks] = a1.v;
    }

    float best[8];
    int bidx[8];
    #pragma unroll
    for (int i = 0; i < 8; ++i) { best[i] = -INFINITY; bidx[i] = 0; }

    asm volatile("s_waitcnt vmcnt(0)" ::: "memory");
    __builtin_amdgcn_s_barrier();

    #pragma unroll
    for (int cc = 0; cc < 2; ++cc) {
        f32x4 acc[2][8];
        #pragma unroll
        for (int rt = 0; rt < 2; ++rt)
            #pragma unroll
            for (int ct = 0; ct < 8; ++ct)
                acc[rt][ct] = (f32x4)(0.f);

        #pragma unroll
        for (int ks = 0; ks < 8; ++ks) {
            int s = cc * 8 + ks;
            int buf = s & 1;
            // issue next stage, wait own stage-s loads (4 newest stay in flight)
            if (s < 15) {
                if (ks < 7) STAGE(cc, ks + 1, buf ^ 1);
                else        STAGE(cc + 1, 0, buf ^ 1);
                asm volatile("s_waitcnt vmcnt(4)" ::: "memory");
            } else {
                asm volatile("s_waitcnt vmcnt(0)" ::: "memory");
            }
            __builtin_amdgcn_s_barrier();   // stage s visible to all waves

            const short* lbase = &sB[buf][(qt * 8) * 512 + l * 8];
            __builtin_amdgcn_s_setprio(1);
            #pragma unroll
            for (int ct = 0; ct < 8; ++ct) {
                bf16x8 bh = *(const bf16x8*)(lbase + ct * 512);
                acc[0][ct] = __builtin_amdgcn_mfma_f32_16x16x32_bf16(ahs0[ks], bh, acc[0][ct], 0, 0, 0);
                acc[1][ct] = __builtin_amdgcn_mfma_f32_16x16x32_bf16(ahs1[ks], bh, acc[1][ct], 0, 0, 0);
            }
            __builtin_amdgcn_s_setprio(0);
            asm volatile("" ::: "memory");
            __builtin_amdgcn_s_barrier();   // all reads of buf done before overwrite
        }
        // epilogue for this 128-col chunk of our quarter (registers only)
        #pragma unroll
        for (int rt = 0; rt < 2; ++rt) {
            #pragma unroll
            for (int ct = 0; ct < 8; ++ct) {
                int col = qt * 256 + cc * 128 + ct * 16 + (l & 15);
                float sq = esq[col];
                #pragma unroll
                for (int v = 0; v < 4; ++v) {
                    float s2 = 2.f * acc[rt][ct][v] - sq;
                    int bi = rt * 4 + v;
                    if (s2 > best[bi]) { best[bi] = s2; bidx[bi] = col; }
                }
            }
        }
    }
#undef STAGE

    // reduce across the 16 lanes holding different cols of the same rows
    #pragma unroll
    for (int bi = 0; bi < 8; ++bi) {
        float bv = best[bi]; int ix = bidx[bi];
        #pragma unroll
        for (int m = 1; m < 16; m <<= 1) {
            float ov = __shfl_xor(bv, m, 64);
            int oi = __shfl_xor(ix, m, 64);
            if (ov > bv || (ov == bv && oi < ix)) { bv = ov; ix = oi; }
        }
        if ((l & 15) == 0) {
            int rt = bi >> 2, v = bi & 3;
            sval[w][rt * 16 + aseg * 4 + v] = bv;
            sidx[w][rt * 16 + aseg * 4 + v] = ix;
        }
    }
    __syncthreads();
    // merge 4 col-quarters: 64 rows per block. qt ascending => lowest col wins ties.
    if (tid < 64) {
        int r = tid & 31;
        int g2 = tid >> 5;                 // row group
        float bv = sval[g2 * 4][r];
        int ix = sidx[g2 * 4][r];
        #pragma unroll
        for (int q2 = 1; q2 < 4; ++q2) {
            float ov = sval[g2 * 4 + q2][r];
            int oi = sidx[g2 * 4 + q2][r];
            if (ov > bv) { bv = ov; ix = oi; }
        }
        idxbuf[blockIdx.x * 64 + g2 * 32 + r] = ix;
    }
}

// ---------------- per-code: quant_st, dw, counts, loss (no fp atomics) ----
#define QCAP 2048
__global__ __launch_bounds__(256) void percode_kernel(
    const float* __restrict__ X,
    const float* __restrict__ E,
    const int* __restrict__ idxbuf,
    float* __restrict__ out_qst,
    float* __restrict__ dwT,
    float* __restrict__ counts,
    float* __restrict__ lossp)
{
    __shared__ int queue[4][QCAP];
    __shared__ float redA[4][256];
    __shared__ float redL[4];
    __shared__ int redC[4];

    int k = blockIdx.x;
    int tid = threadIdx.x;
    int w = tid >> 6, lane = tid & 63;

    float q0 = E[(lane * 4 + 0) * K_CODES + k];
    float q1 = E[(lane * 4 + 1) * K_CODES + k];
    float q2 = E[(lane * 4 + 2) * K_CODES + k];
    float q3 = E[(lane * 4 + 3) * K_CODES + k];

    const float4* X4 = (const float4*)X;
    float4* O4 = (float4*)out_qst;
    const int4* I4 = (const int4*)idxbuf;

    float a0 = 0.f, a1 = 0.f, a2 = 0.f, a3 = 0.f, ls = 0.f;
    int tot = 0, cnt = 0;
    unsigned long long below_mask = (lane == 0) ? 0ull : (~0ull >> (64 - lane));

#define DRAIN() do {                                                        \
        for (int qi = 0; qi < cnt; ++qi) {                                  \
            int row = queue[w][qi];                                         \
            float4 x = X4[(size_t)row * 64 + lane];                         \
            float d0 = q0 - x.x, d1 = q1 - x.y, d2 = q2 - x.z, d3 = q3 - x.w; \
            float4 o; o.x = x.x + d0; o.y = x.y + d1;                       \
            o.z = x.z + d2; o.w = x.w + d3;                                 \
            O4[(size_t)row * 64 + lane] = o;                                \
            a0 += x.x; a1 += x.y; a2 += x.z; a3 += x.w;                     \
            ls += d0 * d0 + d1 * d1 + d2 * d2 + d3 * d3;                    \
        }                                                                   \
        tot += cnt; cnt = 0;                                                \
    } while (0)

    int base = w * 2048;   // int4 units
    for (int it = 0; it < 32; ++it) {
        int4 v = I4[base + it * 64 + lane];
        int rbase = (base + it * 64 + lane) * 4;
        #pragma unroll
        for (int j = 0; j < 4; ++j) {
            int vj = (j == 0) ? v.x : (j == 1) ? v.y : (j == 2) ? v.z : v.w;
            bool p = (vj == k);
            unsigned long long mask = __ballot(p);
            if (p) queue[w][cnt + __popcll(mask & below_mask)] = rbase + j;
            cnt += __popcll(mask);
        }
        if (cnt >= QCAP - 256) DRAIN();
    }
    DRAIN();
#undef DRAIN

    redA[w][lane * 4 + 0] = a0;
    redA[w][lane * 4 + 1] = a1;
    redA[w][lane * 4 + 2] = a2;
    redA[w][lane * 4 + 3] = a3;
    #pragma unroll
    for (int m = 1; m < 64; m <<= 1) ls += __shfl_xor(ls, m, 64);
    if (lane == 0) { redL[w] = ls; redC[w] = tot; }
    __syncthreads();

    float dw = redA[0][tid] + redA[1][tid] + redA[2][tid] + redA[3][tid];
    dwT[(size_t)k * C_DIM + tid] = dw;
    if (tid == 0) {
        lossp[k] = redL[0] + redL[1] + redL[2] + redL[3];
        counts[k] = (float)(redC[0] + redC[1] + redC[2] + redC[3]);
    }
}

// ---------------- finalize 1: cs EMA, n, smoothing, entropy, loss ----------------
__global__ __launch_bounds__(1024) void finalize1_kernel(const float* __restrict__ ema_cs,
                                                         const float* __restrict__ counts,
                                                         const float* __restrict__ lossp,
                                                         float* __restrict__ out,
                                                         float* __restrict__ inv_sm) {
    int k = threadIdx.x;
    __shared__ double red[1024];
    float cs = counts[k];
    float necs = ema_cs[k] * DECAY_F + cs * ONE_MINUS_DECAY;
    out[OFF_CS + k] = necs;

    red[k] = (double)necs;
    __syncthreads();
    for (int s = 512; s > 0; s >>= 1) {
        if (k < s) red[k] += red[k + s];
        __syncthreads();
    }
    float nf = (float)red[0];
    __syncthreads();

    float sm = (necs + EPS_F) / (nf + (float)K_CODES * EPS_F) * nf;
    inv_sm[k] = 1.0f / sm;

    float avg = cs * (1.0f / (float)N_ROWS);
    red[k] = (double)(avg * logf(avg + 1e-10f));
    __syncthreads();
    for (int s = 512; s > 0; s >>= 1) {
        if (k < s) red[k] += red[k + s];
        __syncthreads();
    }
    double ent = red[0];
    __syncthreads();

    red[k] = (double)lossp[k];
    __syncthreads();
    for (int s = 512; s > 0; s >>= 1) {
        if (k < s) red[k] += red[k + s];
        __syncthreads();
    }
    if (k == 0) {
        double eloss = red[0] / (double)(N_ROWS * C_DIM);
        out[OFF_LOSS] = (float)(0.25 * eloss);
        out[OFF_PERP] = expf((float)(-ent));
    }
}

// ---------------- finalize 2: new_ema_dw, new_embeddings ----------------
__global__ __launch_bounds__(256) void finalize2_kernel(const float* __restrict__ ema_dw,
                                                        const float* __restrict__ dwT,
                                                        const float* __restrict__ inv_sm,
                                                        float* __restrict__ out) {
    int i = blockIdx.x * 256 + threadIdx.x;
    int c = i >> 10;
    int k = i & 1023;
    float ndw = ema_dw[i] * DECAY_F + dwT[k * C_DIM + c] * ONE_MINUS_DECAY;
    out[OFF_DW + i] = ndw;
    out[OFF_EMB + i] = ndw * inv_sm[k];
}

extern "C" void kernel_launch(void* const* d_in, const int* in_sizes, int n_in,
                              void* d_out, int out_size, void* d_ws, size_t ws_size,
                              hipStream_t stream) {
    const float* inputs = (const float*)d_in[0];
    const float* E      = (const float*)d_in[1];
    const float* ema_cs = (const float*)d_in[2];
    const float* ema_dw = (const float*)d_in[3];
    float* out = (float*)d_out;
    float* ws  = (float*)d_ws;

    float* esq    = ws + WS_ESQ;
    short* Bp     = (short*)(ws + WS_BP);
    float* dwT    = ws + WS_DWT;
    float* counts = ws + WS_CNT;
    float* lossp  = ws + WS_LOSSP;
    float* inv_sm = ws + WS_INVSM;
    int*   idxbuf = (int*)(ws + WS_IDX);

    esq_kernel<<<K_CODES / 256, 256, 0, stream>>>(E, esq);
    b_pack_kernel<<<128, 256, 0, stream>>>(E, Bp);
    mfma_dist_kernel<<<N_ROWS / 64, 512, 0, stream>>>(inputs, Bp, esq, idxbuf);
    percode_kernel<<<K_CODES, 256, 0, stream>>>(inputs, E, idxbuf, out + OFF_QST,
                                                dwT, counts, lossp);
    finalize1_kernel<<<1, 1024, 0, stream>>>(ema_cs, counts, lossp, out, inv_sm);
    finalize2_kernel<<<(C_DIM * K_CODES) / 256, 256, 0, stream>>>(ema_dw, dwT, inv_sm, out);
}

// Round 8
// 97.314 us; speedup vs baseline: 1.5177x; 1.0406x over previous
//
#include <hip/hip_runtime.h>
#include <hip/hip_bf16.h>
#include <math.h>

#define N_ROWS 32768
#define C_DIM 256
#define K_CODES 1024
#define DECAY_F 0.99f
#define ONE_MINUS_DECAY 0.01f
#define EPS_F 1e-5f

// Output offsets (floats)
#define OFF_QST 0
#define OFF_EMB 8388608
#define OFF_CS  8650752
#define OFF_DW  8651776
#define OFF_LOSS 8913920
#define OFF_PERP 8913921

// Workspace layout (float offsets)
#define WS_ESQ   0         // 1024
#define WS_BP    1024      // 131072 floats = 512KB bf16-packed E (hi only)
#define WS_DWT   132096    // 262144  dwT[k][c]
#define WS_CNT   394240    // 1024
#define WS_LOSSP 395264    // 1024
#define WS_INVSM 396288    // 1024
#define WS_KEYS  397312    // 65536 floats = 32768 u64 argmax keys

typedef __attribute__((ext_vector_type(8))) short bf16x8;
typedef __attribute__((ext_vector_type(4))) float f32x4;
typedef union { short s[8]; unsigned u[4]; bf16x8 v; } fragu;

#define GLD_LDS16(g, l) __builtin_amdgcn_global_load_lds( \
    (const __attribute__((address_space(1))) void*)(g),   \
    (__attribute__((address_space(3))) void*)(l), 16, 0, 0)

__device__ inline unsigned bf16rne(float f) {
    unsigned u = __float_as_uint(f);
    return (u + 0x7fffu + ((u >> 16) & 1u)) >> 16;
}

__device__ inline unsigned pack_bf16_pair(float a, float b) {
    float2 f2; f2.x = a; f2.y = b;
    __hip_bfloat162 h = __float22bfloat162_rn(f2);   // v_cvt_pk_bf16_f32
    union { __hip_bfloat162 b2; unsigned u; } cv;
    cv.b2 = h;
    return cv.u;
}

// monotone float->uint mapping (preserves order incl. negatives)
__device__ inline unsigned sortable_f32(float f) {
    unsigned u = __float_as_uint(f);
    return (u & 0x80000000u) ? ~u : (u | 0x80000000u);
}

// ---------------- prep: esq[k] = sum_d E[d,k]^2 (fp32 exact) --------------
__global__ __launch_bounds__(256) void esq_kernel(const float* __restrict__ E,
                                                  float* __restrict__ esq) {
    int k = blockIdx.x * 256 + threadIdx.x;
    float s = 0.f;
    #pragma unroll 8
    for (int d = 0; d < C_DIM; ++d) {
        float e = E[d * K_CODES + k];
        s += e * e;
    }
    esq[k] = s;
}

// ---------------- prep: pack E (hi bf16) into MFMA B layout ----------
// Group g = ctg*8 + ks (ctg 0..63 col-tile, ks 0..7 k-step).
// Lane l: 8 bf16, col = ctg*16+(l&15), k = ks*32 + (l>>4)*8 + b.
__global__ __launch_bounds__(256) void b_pack_kernel(const float* __restrict__ E,
                                                     short* __restrict__ Bp) {
    int tid = threadIdx.x;
    int g = blockIdx.x * 4 + (tid >> 6);
    int l = tid & 63;
    int ct = g >> 3, ks = g & 7;
    int j = ct * 16 + (l & 15);
    int kbase = ks * 32 + (l >> 4) * 8;
    fragu out;
    #pragma unroll
    for (int b = 0; b < 8; ++b)
        out.s[b] = (short)bf16rne(E[(kbase + b) * K_CODES + j]);
    *(bf16x8*)(Bp + ((size_t)g * 64 + l) * 8) = out.v;
}

// ---------------- MFMA distance + fused argmax ----------------
// 512 blocks x 4 waves (256 thr). Block = 128 rows x 512 cols (chalf=bid&1).
// All 4 waves share cols; wave w owns rows w*32..w*32+31 (rt=2 row-tiles).
// A (bf16) in registers for the whole kernel. K=256 fully accumulated.
// Phases p = cc*8+ks (cc 0..3: 128-col chunk, ks 0..7): stage = 8 groups x 1KB
// = 8KB into a 5-slot LDS ring; depth-3 in-flight, vmcnt(6), ONE barrier/phase.
// Cross-chalf argmax merge via sortable-key atomicMax (deterministic).
__global__ __launch_bounds__(256) void mfma_dist_kernel(
    const float* __restrict__ X,
    const short* __restrict__ Bp,
    const float* __restrict__ esq,
    unsigned long long* __restrict__ keys)
{
    __shared__ short sB[5][4096];    // 5 x 8KB ring

    int tid = threadIdx.x;
    int w = tid >> 6, l = tid & 63;
    int brow = blockIdx.x >> 1;
    int chalf = blockIdx.x & 1;
    int row0 = brow * 128 + w * 32;
    int arow = l & 15;
    int aseg = l >> 4;
    const float* Xr0 = X + (size_t)(row0 + arow) * C_DIM + aseg * 8;
    const float* Xr1 = Xr0 + 16 * C_DIM;

    // stage phase (cc_,ks_) into ring slot sl: 2 loads/wave; q = i*4+w in 0..7
    // covers col-tiles ctg = chalf*32 + cc_*8 + q, one ks each; 1KB per group.
#define STAGE(cc_, ks_, sl) do {                                             \
        _Pragma("unroll")                                                    \
        for (int i = 0; i < 2; ++i) {                                        \
            int q = i * 4 + w;                                               \
            int ctg = chalf * 32 + (cc_) * 8 + q;                            \
            const short* src = Bp + ((size_t)(ctg * 8 + (ks_)) * 64 + l) * 8;\
            GLD_LDS16(src, &sB[sl][q * 512]);                                 \
        }                                                                    \
    } while (0)

    // prologue: stages for phases 0,1,2
    STAGE(0, 0, 0);
    STAGE(0, 1, 1);
    STAGE(0, 2, 2);

    // load + convert all A fragments (once); consuming waits drain vmcnt,
    // so stage 0-2 (older) are retired before the phase loop begins.
    bf16x8 ahs0[8], ahs1[8];
    #pragma unroll
    for (int ks = 0; ks < 8; ++ks) {
        float xf0[8], xf1[8];
        *(float4*)(xf0)     = *(const float4*)(Xr0 + ks * 32);
        *(float4*)(xf0 + 4) = *(const float4*)(Xr0 + ks * 32 + 4);
        *(float4*)(xf1)     = *(const float4*)(Xr1 + ks * 32);
        *(float4*)(xf1 + 4) = *(const float4*)(Xr1 + ks * 32 + 4);
        fragu a0, a1;
        #pragma unroll
        for (int p = 0; p < 4; ++p) {
            a0.u[p] = pack_bf16_pair(xf0[2 * p], xf0[2 * p + 1]);
            a1.u[p] = pack_bf16_pair(xf1[2 * p], xf1[2 * p + 1]);
        }
        ahs0[ks] = a0.v;
        ahs1[ks] = a1.v;
    }

    float best[8];
    int bidx[8];
    #pragma unroll
    for (int i = 0; i < 8; ++i) { best[i] = -INFINITY; bidx[i] = 0; }

    #pragma unroll
    for (int cc = 0; cc < 4; ++cc) {
        f32x4 acc[2][8];
        #pragma unroll
        for (int rt = 0; rt < 2; ++rt)
            #pragma unroll
            for (int ct = 0; ct < 8; ++ct)
                acc[rt][ct] = (f32x4)(0.f);

        #pragma unroll
        for (int ks = 0; ks < 8; ++ks) {
            const int p = cc * 8 + ks;
            const int slot = p % 5;
            // issue stage p+3 (safe: slot (p+3)%5 last read at phase p-2,
            // retired before every wave passed barrier p-1)
            if (p < 29) {
                const int pn = p + 3;
                STAGE(pn >> 3, pn & 7, pn % 5);
            }
            // counted wait: stage p complete, stages p+1..p+3 stay in flight
            if (p < 29)      asm volatile("s_waitcnt vmcnt(6)" ::: "memory");
            else if (p == 29) asm volatile("s_waitcnt vmcnt(4)" ::: "memory");
            else if (p == 30) asm volatile("s_waitcnt vmcnt(2)" ::: "memory");
            else              asm volatile("s_waitcnt vmcnt(0)" ::: "memory");
            __builtin_amdgcn_s_barrier();   // publishes stage p to all waves
            asm volatile("" ::: "memory");

            const short* lbase = &sB[slot][l * 8];
            __builtin_amdgcn_s_setprio(1);
            #pragma unroll
            for (int ct = 0; ct < 8; ++ct) {
                bf16x8 bh = *(const bf16x8*)(lbase + ct * 512);
                acc[0][ct] = __builtin_amdgcn_mfma_f32_16x16x32_bf16(ahs0[ks], bh, acc[0][ct], 0, 0, 0);
                acc[1][ct] = __builtin_amdgcn_mfma_f32_16x16x32_bf16(ahs1[ks], bh, acc[1][ct], 0, 0, 0);
            }
            __builtin_amdgcn_s_setprio(0);
        }
        // epilogue for this 128-col chunk (registers only; no sync needed)
        #pragma unroll
        for (int rt = 0; rt < 2; ++rt) {
            #pragma unroll
            for (int ct = 0; ct < 8; ++ct) {
                int col = chalf * 512 + cc * 128 + ct * 16 + (l & 15);
                float sq = esq[col];
                #pragma unroll
                for (int v = 0; v < 4; ++v) {
                    float s2 = 2.f * acc[rt][ct][v] - sq;
                    int bi = rt * 4 + v;
                    if (s2 > best[bi]) { best[bi] = s2; bidx[bi] = col; }
                }
            }
        }
    }
#undef STAGE

    // reduce across the 16 lanes holding different cols of the same rows,
    // then merge col-halves via atomicMax on a sortable key (min-idx ties).
    #pragma unroll
    for (int bi = 0; bi < 8; ++bi) {
        float bv = best[bi]; int ix = bidx[bi];
        #pragma unroll
        for (int m = 1; m < 16; m <<= 1) {
            float ov = __shfl_xor(bv, m, 64);
            int oi = __shfl_xor(ix, m, 64);
            if (ov > bv || (ov == bv && oi < ix)) { bv = ov; ix = oi; }
        }
        if ((l & 15) == 0) {
            int row = row0 + (bi >> 2) * 16 + aseg * 4 + (bi & 3);
            unsigned long long key =
                ((unsigned long long)sortable_f32(bv) << 32) |
                (unsigned long long)(0xffffffffu - (unsigned)ix);
            atomicMax(&keys[row], key);
        }
    }
}

// ---------------- per-code: quant_st, dw, counts, loss (no fp atomics) ----
#define QCAP 2048
__global__ __launch_bounds__(256) void percode_kernel(
    const float* __restrict__ X,
    const float* __restrict__ E,
    const unsigned long long* __restrict__ keys,
    float* __restrict__ out_qst,
    float* __restrict__ dwT,
    float* __restrict__ counts,
    float* __restrict__ lossp)
{
    __shared__ int queue[4][QCAP];
    __shared__ float redA[4][256];
    __shared__ float redL[4];
    __shared__ int redC[4];

    int k = blockIdx.x;
    int tid = threadIdx.x;
    int w = tid >> 6, lane = tid & 63;

    float q0 = E[(lane * 4 + 0) * K_CODES + k];
    float q1 = E[(lane * 4 + 1) * K_CODES + k];
    float q2 = E[(lane * 4 + 2) * K_CODES + k];
    float q3 = E[(lane * 4 + 3) * K_CODES + k];

    const float4* X4 = (const float4*)X;
    float4* O4 = (float4*)out_qst;
    const ulonglong2* K2 = (const ulonglong2*)keys;

    float a0 = 0.f, a1 = 0.f, a2 = 0.f, a3 = 0.f, ls = 0.f;
    int tot = 0, cnt = 0;
    unsigned long long below_mask = (lane == 0) ? 0ull : (~0ull >> (64 - lane));

#define DRAIN() do {                                                        \
        for (int qi = 0; qi < cnt; ++qi) {                                  \
            int row = queue[w][qi];                                         \
            float4 x = X4[(size_t)row * 64 + lane];                         \
            float d0 = q0 - x.x, d1 = q1 - x.y, d2 = q2 - x.z, d3 = q3 - x.w; \
            float4 o; o.x = x.x + d0; o.y = x.y + d1;                       \
            o.z = x.z + d2; o.w = x.w + d3;                                 \
            O4[(size_t)row * 64 + lane] = o;                                \
            a0 += x.x; a1 += x.y; a2 += x.z; a3 += x.w;                     \
            ls += d0 * d0 + d1 * d1 + d2 * d2 + d3 * d3;                    \
        }                                                                   \
        tot += cnt; cnt = 0;                                                \
    } while (0)

    int base = w * 4096;   // ull2 units; wave quarter = 8192 keys
    for (int it = 0; it < 64; ++it) {
        ulonglong2 kv = K2[base + it * 64 + lane];
        int r0 = (base + it * 64 + lane) * 2;
        int i0 = (int)(0xffffffffu - (unsigned)(kv.x & 0xffffffffull));
        int i1 = (int)(0xffffffffu - (unsigned)(kv.y & 0xffffffffull));
        {
            bool p = (i0 == k);
            unsigned long long mask = __ballot(p);
            if (p) queue[w][cnt + __popcll(mask & below_mask)] = r0;
            cnt += __popcll(mask);
        }
        {
            bool p = (i1 == k);
            unsigned long long mask = __ballot(p);
            if (p) queue[w][cnt + __popcll(mask & below_mask)] = r0 + 1;
            cnt += __popcll(mask);
        }
        if (cnt >= QCAP - 256) DRAIN();
    }
    DRAIN();
#undef DRAIN

    redA[w][lane * 4 + 0] = a0;
    redA[w][lane * 4 + 1] = a1;
    redA[w][lane * 4 + 2] = a2;
    redA[w][lane * 4 + 3] = a3;
    #pragma unroll
    for (int m = 1; m < 64; m <<= 1) ls += __shfl_xor(ls, m, 64);
    if (lane == 0) { redL[w] = ls; redC[w] = tot; }
    __syncthreads();

    float dw = redA[0][tid] + redA[1][tid] + redA[2][tid] + redA[3][tid];
    dwT[(size_t)k * C_DIM + tid] = dw;
    if (tid == 0) {
        lossp[k] = redL[0] + redL[1] + redL[2] + redL[3];
        counts[k] = (float)(redC[0] + redC[1] + redC[2] + redC[3]);
    }
}

// ---------------- finalize 1: cs EMA, n, smoothing, entropy, loss ----------------
__global__ __launch_bounds__(1024) void finalize1_kernel(const float* __restrict__ ema_cs,
                                                         const float* __restrict__ counts,
                                                         const float* __restrict__ lossp,
                                                         float* __restrict__ out,
                                                         float* __restrict__ inv_sm) {
    int k = threadIdx.x;
    __shared__ double red[1024];
    float cs = counts[k];
    float necs = ema_cs[k] * DECAY_F + cs * ONE_MINUS_DECAY;
    out[OFF_CS + k] = necs;

    red[k] = (double)necs;
    __syncthreads();
    for (int s = 512; s > 0; s >>= 1) {
        if (k < s) red[k] += red[k + s];
        __syncthreads();
    }
    float nf = (float)red[0];
    __syncthreads();

    float sm = (necs + EPS_F) / (nf + (float)K_CODES * EPS_F) * nf;
    inv_sm[k] = 1.0f / sm;

    float avg = cs * (1.0f / (float)N_ROWS);
    red[k] = (double)(avg * logf(avg + 1e-10f));
    __syncthreads();
    for (int s = 512; s > 0; s >>= 1) {
        if (k < s) red[k] += red[k + s];
        __syncthreads();
    }
    double ent = red[0];
    __syncthreads();

    red[k] = (double)lossp[k];
    __syncthreads();
    for (int s = 512; s > 0; s >>= 1) {
        if (k < s) red[k] += red[k + s];
        __syncthreads();
    }
    if (k == 0) {
        double eloss = red[0] / (double)(N_ROWS * C_DIM);
        out[OFF_LOSS] = (float)(0.25 * eloss);
        out[OFF_PERP] = expf((float)(-ent));
    }
}

// ---------------- finalize 2: new_ema_dw, new_embeddings ----------------
__global__ __launch_bounds__(256) void finalize2_kernel(const float* __restrict__ ema_dw,
                                                        const float* __restrict__ dwT,
                                                        const float* __restrict__ inv_sm,
                                                        float* __restrict__ out) {
    int i = blockIdx.x * 256 + threadIdx.x;
    int c = i >> 10;
    int k = i & 1023;
    float ndw = ema_dw[i] * DECAY_F + dwT[k * C_DIM + c] * ONE_MINUS_DECAY;
    out[OFF_DW + i] = ndw;
    out[OFF_EMB + i] = ndw * inv_sm[k];
}

extern "C" void kernel_launch(void* const* d_in, const int* in_sizes, int n_in,
                              void* d_out, int out_size, void* d_ws, size_t ws_size,
                              hipStream_t stream) {
    const float* inputs = (const float*)d_in[0];
    const float* E      = (const float*)d_in[1];
    const float* ema_cs = (const float*)d_in[2];
    const float* ema_dw = (const float*)d_in[3];
    float* out = (float*)d_out;
    float* ws  = (float*)d_ws;

    float* esq    = ws + WS_ESQ;
    short* Bp     = (short*)(ws + WS_BP);
    float* dwT    = ws + WS_DWT;
    float* counts = ws + WS_CNT;
    float* lossp  = ws + WS_LOSSP;
    float* inv_sm = ws + WS_INVSM;
    unsigned long long* keys = (unsigned long long*)(ws + WS_KEYS);

    // zero argmax keys (atomicMax accumulator; must be < any real key)
    hipMemsetAsync(keys, 0, (size_t)N_ROWS * sizeof(unsigned long long), stream);

    esq_kernel<<<K_CODES / 256, 256, 0, stream>>>(E, esq);
    b_pack_kernel<<<128, 256, 0, stream>>>(E, Bp);
    mfma_dist_kernel<<<512, 256, 0, stream>>>(inputs, Bp, esq, keys);
    percode_kernel<<<K_CODES, 256, 0, stream>>>(inputs, E, keys, out + OFF_QST,
                                                dwT, counts, lossp);
    finalize1_kernel<<<1, 1024, 0, stream>>>(ema_cs, counts, lossp, out, inv_sm);
    finalize2_kernel<<<(C_DIM * K_CODES) / 256, 256, 0, stream>>>(ema_dw, dwT, inv_sm, out);
}

// Round 9
// 91.954 us; speedup vs baseline: 1.6062x; 1.0583x over previous
//
#include <hip/hip_runtime.h>
#include <hip/hip_bf16.h>
#include <math.h>

#define N_ROWS 32768
#define C_DIM 256
#define K_CODES 1024
#define DECAY_F 0.99f
#define ONE_MINUS_DECAY 0.01f
#define EPS_F 1e-5f

// Output offsets (floats)
#define OFF_QST 0
#define OFF_EMB 8388608
#define OFF_CS  8650752
#define OFF_DW  8651776
#define OFF_LOSS 8913920
#define OFF_PERP 8913921

// Workspace layout (float offsets)
#define WS_ESQ   0         // 1024
#define WS_BP    1024      // 131072 floats = 512KB bf16-packed E (hi only)
#define WS_DWT   132096    // 262144  dwT[k][c]
#define WS_CNT   394240    // 1024
#define WS_LOSSP 395264    // 1024
#define WS_INVSM 396288    // 1024
#define WS_KEYS  397312    // 65536 floats = 32768 u64 argmax keys

typedef __attribute__((ext_vector_type(8))) short bf16x8;
typedef __attribute__((ext_vector_type(4))) float f32x4;
typedef union { short s[8]; unsigned u[4]; bf16x8 v; } fragu;

#define GLD_LDS16(g, l) __builtin_amdgcn_global_load_lds( \
    (const __attribute__((address_space(1))) void*)(g),   \
    (__attribute__((address_space(3))) void*)(l), 16, 0, 0)

__device__ inline unsigned bf16rne(float f) {
    unsigned u = __float_as_uint(f);
    return (u + 0x7fffu + ((u >> 16) & 1u)) >> 16;
}

__device__ inline unsigned pack_bf16_pair(float a, float b) {
    float2 f2; f2.x = a; f2.y = b;
    __hip_bfloat162 h = __float22bfloat162_rn(f2);   // v_cvt_pk_bf16_f32
    union { __hip_bfloat162 b2; unsigned u; } cv;
    cv.b2 = h;
    return cv.u;
}

// monotone float->uint mapping (preserves order incl. negatives)
__device__ inline unsigned sortable_f32(float f) {
    unsigned u = __float_as_uint(f);
    return (u & 0x80000000u) ? ~u : (u | 0x80000000u);
}

// ---------------- prep: esq[k] = sum_d E[d,k]^2 (fp32 exact) --------------
__global__ __launch_bounds__(256) void esq_kernel(const float* __restrict__ E,
                                                  float* __restrict__ esq) {
    int k = blockIdx.x * 256 + threadIdx.x;
    float s = 0.f;
    #pragma unroll 8
    for (int d = 0; d < C_DIM; ++d) {
        float e = E[d * K_CODES + k];
        s += e * e;
    }
    esq[k] = s;
}

// ---------------- prep: pack E (hi bf16) into MFMA B layout + zero keys ---
// Group g = ctg*8 + ks (ctg 0..63 col-tile, ks 0..7 k-step).
// Lane l: 8 bf16, col = ctg*16+(l&15), k = ks*32 + (l>>4)*8 + b.
// Also zeroes the per-row argmax key array (exactly 32768 threads):
// replaces a hipMemsetAsync whose fill kernel cost 40us (tiny-grid bound).
__global__ __launch_bounds__(256) void b_pack_kernel(const float* __restrict__ E,
                                                     short* __restrict__ Bp,
                                                     unsigned long long* __restrict__ keys) {
    int tid = threadIdx.x;
    keys[blockIdx.x * 256 + tid] = 0ull;
    int g = blockIdx.x * 4 + (tid >> 6);
    int l = tid & 63;
    int ct = g >> 3, ks = g & 7;
    int j = ct * 16 + (l & 15);
    int kbase = ks * 32 + (l >> 4) * 8;
    fragu out;
    #pragma unroll
    for (int b = 0; b < 8; ++b)
        out.s[b] = (short)bf16rne(E[(kbase + b) * K_CODES + j]);
    *(bf16x8*)(Bp + ((size_t)g * 64 + l) * 8) = out.v;
}

// ---------------- MFMA distance + fused argmax ----------------
// 512 blocks x 4 waves (256 thr). Block = 128 rows x 512 cols (chalf=bid&1).
// All 4 waves share cols; wave w owns rows w*32..w*32+31 (rt=2 row-tiles).
// A (bf16) in registers for the whole kernel. K=256 fully accumulated.
// Phases p = cc*8+ks (cc 0..3: 128-col chunk, ks 0..7): stage = 8 groups x 1KB
// = 8KB into a 5-slot LDS ring; depth-3 in-flight, vmcnt(6), ONE barrier/phase.
// Cross-chalf argmax merge via sortable-key atomicMax (deterministic).
__global__ __launch_bounds__(256) void mfma_dist_kernel(
    const float* __restrict__ X,
    const short* __restrict__ Bp,
    const float* __restrict__ esq,
    unsigned long long* __restrict__ keys)
{
    __shared__ short sB[5][4096];    // 5 x 8KB ring

    int tid = threadIdx.x;
    int w = tid >> 6, l = tid & 63;
    int brow = blockIdx.x >> 1;
    int chalf = blockIdx.x & 1;
    int row0 = brow * 128 + w * 32;
    int arow = l & 15;
    int aseg = l >> 4;
    const float* Xr0 = X + (size_t)(row0 + arow) * C_DIM + aseg * 8;
    const float* Xr1 = Xr0 + 16 * C_DIM;

    // stage phase (cc_,ks_) into ring slot sl: 2 loads/wave; q = i*4+w in 0..7
    // covers col-tiles ctg = chalf*32 + cc_*8 + q, one ks each; 1KB per group.
#define STAGE(cc_, ks_, sl) do {                                             \
        _Pragma("unroll")                                                    \
        for (int i = 0; i < 2; ++i) {                                        \
            int q = i * 4 + w;                                               \
            int ctg = chalf * 32 + (cc_) * 8 + q;                            \
            const short* src = Bp + ((size_t)(ctg * 8 + (ks_)) * 64 + l) * 8;\
            GLD_LDS16(src, &sB[sl][q * 512]);                                 \
        }                                                                    \
    } while (0)

    // prologue: stages for phases 0,1,2
    STAGE(0, 0, 0);
    STAGE(0, 1, 1);
    STAGE(0, 2, 2);

    // load + convert all A fragments (once); consuming waits drain vmcnt,
    // so stage 0-2 (older) are retired before the phase loop begins.
    bf16x8 ahs0[8], ahs1[8];
    #pragma unroll
    for (int ks = 0; ks < 8; ++ks) {
        float xf0[8], xf1[8];
        *(float4*)(xf0)     = *(const float4*)(Xr0 + ks * 32);
        *(float4*)(xf0 + 4) = *(const float4*)(Xr0 + ks * 32 + 4);
        *(float4*)(xf1)     = *(const float4*)(Xr1 + ks * 32);
        *(float4*)(xf1 + 4) = *(const float4*)(Xr1 + ks * 32 + 4);
        fragu a0, a1;
        #pragma unroll
        for (int p = 0; p < 4; ++p) {
            a0.u[p] = pack_bf16_pair(xf0[2 * p], xf0[2 * p + 1]);
            a1.u[p] = pack_bf16_pair(xf1[2 * p], xf1[2 * p + 1]);
        }
        ahs0[ks] = a0.v;
        ahs1[ks] = a1.v;
    }

    float best[8];
    int bidx[8];
    #pragma unroll
    for (int i = 0; i < 8; ++i) { best[i] = -INFINITY; bidx[i] = 0; }

    #pragma unroll
    for (int cc = 0; cc < 4; ++cc) {
        f32x4 acc[2][8];
        #pragma unroll
        for (int rt = 0; rt < 2; ++rt)
            #pragma unroll
            for (int ct = 0; ct < 8; ++ct)
                acc[rt][ct] = (f32x4)(0.f);

        #pragma unroll
        for (int ks = 0; ks < 8; ++ks) {
            const int p = cc * 8 + ks;
            const int slot = p % 5;
            // issue stage p+3 (safe: slot (p+3)%5 last read at phase p-2,
            // retired before every wave passed barrier p-1)
            if (p < 29) {
                const int pn = p + 3;
                STAGE(pn >> 3, pn & 7, pn % 5);
            }
            // counted wait: stage p complete, stages p+1..p+3 stay in flight
            if (p < 29)      asm volatile("s_waitcnt vmcnt(6)" ::: "memory");
            else if (p == 29) asm volatile("s_waitcnt vmcnt(4)" ::: "memory");
            else if (p == 30) asm volatile("s_waitcnt vmcnt(2)" ::: "memory");
            else              asm volatile("s_waitcnt vmcnt(0)" ::: "memory");
            __builtin_amdgcn_s_barrier();   // publishes stage p to all waves
            asm volatile("" ::: "memory");

            const short* lbase = &sB[slot][l * 8];
            __builtin_amdgcn_s_setprio(1);
            #pragma unroll
            for (int ct = 0; ct < 8; ++ct) {
                bf16x8 bh = *(const bf16x8*)(lbase + ct * 512);
                acc[0][ct] = __builtin_amdgcn_mfma_f32_16x16x32_bf16(ahs0[ks], bh, acc[0][ct], 0, 0, 0);
                acc[1][ct] = __builtin_amdgcn_mfma_f32_16x16x32_bf16(ahs1[ks], bh, acc[1][ct], 0, 0, 0);
            }
            __builtin_amdgcn_s_setprio(0);
        }
        // epilogue for this 128-col chunk (registers only; no sync needed)
        #pragma unroll
        for (int rt = 0; rt < 2; ++rt) {
            #pragma unroll
            for (int ct = 0; ct < 8; ++ct) {
                int col = chalf * 512 + cc * 128 + ct * 16 + (l & 15);
                float sq = esq[col];
                #pragma unroll
                for (int v = 0; v < 4; ++v) {
                    float s2 = 2.f * acc[rt][ct][v] - sq;
                    int bi = rt * 4 + v;
                    if (s2 > best[bi]) { best[bi] = s2; bidx[bi] = col; }
                }
            }
        }
    }
#undef STAGE

    // reduce across the 16 lanes holding different cols of the same rows,
    // then merge col-halves via atomicMax on a sortable key (min-idx ties).
    #pragma unroll
    for (int bi = 0; bi < 8; ++bi) {
        float bv = best[bi]; int ix = bidx[bi];
        #pragma unroll
        for (int m = 1; m < 16; m <<= 1) {
            float ov = __shfl_xor(bv, m, 64);
            int oi = __shfl_xor(ix, m, 64);
            if (ov > bv || (ov == bv && oi < ix)) { bv = ov; ix = oi; }
        }
        if ((l & 15) == 0) {
            int row = row0 + (bi >> 2) * 16 + aseg * 4 + (bi & 3);
            unsigned long long key =
                ((unsigned long long)sortable_f32(bv) << 32) |
                (unsigned long long)(0xffffffffu - (unsigned)ix);
            atomicMax(&keys[row], key);
        }
    }
}

// ---------------- per-code: quant_st, dw, counts, loss (no fp atomics) ----
#define QCAP 2048
__global__ __launch_bounds__(256) void percode_kernel(
    const float* __restrict__ X,
    const float* __restrict__ E,
    const unsigned long long* __restrict__ keys,
    float* __restrict__ out_qst,
    float* __restrict__ dwT,
    float* __restrict__ counts,
    float* __restrict__ lossp)
{
    __shared__ int queue[4][QCAP];
    __shared__ float redA[4][256];
    __shared__ float redL[4];
    __shared__ int redC[4];

    int k = blockIdx.x;
    int tid = threadIdx.x;
    int w = tid >> 6, lane = tid & 63;

    float q0 = E[(lane * 4 + 0) * K_CODES + k];
    float q1 = E[(lane * 4 + 1) * K_CODES + k];
    float q2 = E[(lane * 4 + 2) * K_CODES + k];
    float q3 = E[(lane * 4 + 3) * K_CODES + k];

    const float4* X4 = (const float4*)X;
    float4* O4 = (float4*)out_qst;
    const ulonglong2* K2 = (const ulonglong2*)keys;

    float a0 = 0.f, a1 = 0.f, a2 = 0.f, a3 = 0.f, ls = 0.f;
    int tot = 0, cnt = 0;
    unsigned long long below_mask = (lane == 0) ? 0ull : (~0ull >> (64 - lane));

#define DRAIN() do {                                                        \
        for (int qi = 0; qi < cnt; ++qi) {                                  \
            int row = queue[w][qi];                                         \
            float4 x = X4[(size_t)row * 64 + lane];                         \
            float d0 = q0 - x.x, d1 = q1 - x.y, d2 = q2 - x.z, d3 = q3 - x.w; \
            float4 o; o.x = x.x + d0; o.y = x.y + d1;                       \
            o.z = x.z + d2; o.w = x.w + d3;                                 \
            O4[(size_t)row * 64 + lane] = o;                                \
            a0 += x.x; a1 += x.y; a2 += x.z; a3 += x.w;                     \
            ls += d0 * d0 + d1 * d1 + d2 * d2 + d3 * d3;                    \
        }                                                                   \
        tot += cnt; cnt = 0;                                                \
    } while (0)

    int base = w * 4096;   // ull2 units; wave quarter = 8192 keys
    for (int it = 0; it < 64; ++it) {
        ulonglong2 kv = K2[base + it * 64 + lane];
        int r0 = (base + it * 64 + lane) * 2;
        int i0 = (int)(0xffffffffu - (unsigned)(kv.x & 0xffffffffull));
        int i1 = (int)(0xffffffffu - (unsigned)(kv.y & 0xffffffffull));
        {
            bool p = (i0 == k);
            unsigned long long mask = __ballot(p);
            if (p) queue[w][cnt + __popcll(mask & below_mask)] = r0;
            cnt += __popcll(mask);
        }
        {
            bool p = (i1 == k);
            unsigned long long mask = __ballot(p);
            if (p) queue[w][cnt + __popcll(mask & below_mask)] = r0 + 1;
            cnt += __popcll(mask);
        }
        if (cnt >= QCAP - 256) DRAIN();
    }
    DRAIN();
#undef DRAIN

    redA[w][lane * 4 + 0] = a0;
    redA[w][lane * 4 + 1] = a1;
    redA[w][lane * 4 + 2] = a2;
    redA[w][lane * 4 + 3] = a3;
    #pragma unroll
    for (int m = 1; m < 64; m <<= 1) ls += __shfl_xor(ls, m, 64);
    if (lane == 0) { redL[w] = ls; redC[w] = tot; }
    __syncthreads();

    float dw = redA[0][tid] + redA[1][tid] + redA[2][tid] + redA[3][tid];
    dwT[(size_t)k * C_DIM + tid] = dw;
    if (tid == 0) {
        lossp[k] = redL[0] + redL[1] + redL[2] + redL[3];
        counts[k] = (float)(redC[0] + redC[1] + redC[2] + redC[3]);
    }
}

// ---------------- finalize 1: cs EMA, n, smoothing, entropy, loss ----------------
__global__ __launch_bounds__(1024) void finalize1_kernel(const float* __restrict__ ema_cs,
                                                         const float* __restrict__ counts,
                                                         const float* __restrict__ lossp,
                                                         float* __restrict__ out,
                                                         float* __restrict__ inv_sm) {
    int k = threadIdx.x;
    __shared__ double red[1024];
    float cs = counts[k];
    float necs = ema_cs[k] * DECAY_F + cs * ONE_MINUS_DECAY;
    out[OFF_CS + k] = necs;

    red[k] = (double)necs;
    __syncthreads();
    for (int s = 512; s > 0; s >>= 1) {
        if (k < s) red[k] += red[k + s];
        __syncthreads();
    }
    float nf = (float)red[0];
    __syncthreads();

    float sm = (necs + EPS_F) / (nf + (float)K_CODES * EPS_F) * nf;
    inv_sm[k] = 1.0f / sm;

    float avg = cs * (1.0f / (float)N_ROWS);
    red[k] = (double)(avg * logf(avg + 1e-10f));
    __syncthreads();
    for (int s = 512; s > 0; s >>= 1) {
        if (k < s) red[k] += red[k + s];
        __syncthreads();
    }
    double ent = red[0];
    __syncthreads();

    red[k] = (double)lossp[k];
    __syncthreads();
    for (int s = 512; s > 0; s >>= 1) {
        if (k < s) red[k] += red[k + s];
        __syncthreads();
    }
    if (k == 0) {
        double eloss = red[0] / (double)(N_ROWS * C_DIM);
        out[OFF_LOSS] = (float)(0.25 * eloss);
        out[OFF_PERP] = expf((float)(-ent));
    }
}

// ---------------- finalize 2: new_ema_dw, new_embeddings ----------------
__global__ __launch_bounds__(256) void finalize2_kernel(const float* __restrict__ ema_dw,
                                                        const float* __restrict__ dwT,
                                                        const float* __restrict__ inv_sm,
                                                        float* __restrict__ out) {
    int i = blockIdx.x * 256 + threadIdx.x;
    int c = i >> 10;
    int k = i & 1023;
    float ndw = ema_dw[i] * DECAY_F + dwT[k * C_DIM + c] * ONE_MINUS_DECAY;
    out[OFF_DW + i] = ndw;
    out[OFF_EMB + i] = ndw * inv_sm[k];
}

extern "C" void kernel_launch(void* const* d_in, const int* in_sizes, int n_in,
                              void* d_out, int out_size, void* d_ws, size_t ws_size,
                              hipStream_t stream) {
    const float* inputs = (const float*)d_in[0];
    const float* E      = (const float*)d_in[1];
    const float* ema_cs = (const float*)d_in[2];
    const float* ema_dw = (const float*)d_in[3];
    float* out = (float*)d_out;
    float* ws  = (float*)d_ws;

    float* esq    = ws + WS_ESQ;
    short* Bp     = (short*)(ws + WS_BP);
    float* dwT    = ws + WS_DWT;
    float* counts = ws + WS_CNT;
    float* lossp  = ws + WS_LOSSP;
    float* inv_sm = ws + WS_INVSM;
    unsigned long long* keys = (unsigned long long*)(ws + WS_KEYS);

    esq_kernel<<<K_CODES / 256, 256, 0, stream>>>(E, esq);
    b_pack_kernel<<<128, 256, 0, stream>>>(E, Bp, keys);   // also zeroes keys
    mfma_dist_kernel<<<512, 256, 0, stream>>>(inputs, Bp, esq, keys);
    percode_kernel<<<K_CODES, 256, 0, stream>>>(inputs, E, keys, out + OFF_QST,
                                                dwT, counts, lossp);
    finalize1_kernel<<<1, 1024, 0, stream>>>(ema_cs, counts, lossp, out, inv_sm);
    finalize2_kernel<<<(C_DIM * K_CODES) / 256, 256, 0, stream>>>(ema_dw, dwT, inv_sm, out);
}